// Round 1
// baseline (2734.600 us; speedup 1.0000x reference)
//
#include <hip/hip_runtime.h>

#define DEVINL __device__ __forceinline__

constexpr int PAD = 36;   // LDS row stride for 32-float rows (breaks bank alias)

DEVINL float lrelu1(float v) { return v > 0.f ? v : 0.2f * v; }

DEVINL float4 lrelu4(const float a[4]) {
    float4 r;
    r.x = lrelu1(a[0]); r.y = lrelu1(a[1]); r.z = lrelu1(a[2]); r.w = lrelu1(a[3]);
    return r;
}
DEVINL float4 relu4(const float a[4]) {
    float4 r;
    r.x = fmaxf(a[0], 0.f); r.y = fmaxf(a[1], 0.f);
    r.z = fmaxf(a[2], 0.f); r.w = fmaxf(a[3], 0.f);
    return r;
}

// Accumulate a 32-K GEMM step: 2 edges (rows es, es+32 of in_s) x 4 channels (4g..4g+3).
// w_s: LDS weights [32][32] row-major. in_s: LDS rows, stride PAD.
DEVINL void gemm32_acc(const float* __restrict__ w_s, const float* __restrict__ in_s,
                       int es, int g, float acc[2][4])
{
#pragma unroll
    for (int kk = 0; kk < 32; kk += 4) {
        float4 hA = *(const float4*)&in_s[es * PAD + kk];
        float4 hB = *(const float4*)&in_s[(es + 32) * PAD + kk];
        float ha[4] = {hA.x, hA.y, hA.z, hA.w};
        float hb[4] = {hB.x, hB.y, hB.z, hB.w};
#pragma unroll
        for (int j = 0; j < 4; ++j) {
            float4 w = *(const float4*)&w_s[(kk + j) * 32 + 4 * g];
            acc[0][0] = fmaf(ha[j], w.x, acc[0][0]);
            acc[0][1] = fmaf(ha[j], w.y, acc[0][1]);
            acc[0][2] = fmaf(ha[j], w.z, acc[0][2]);
            acc[0][3] = fmaf(ha[j], w.w, acc[0][3]);
            acc[1][0] = fmaf(hb[j], w.x, acc[1][0]);
            acc[1][1] = fmaf(hb[j], w.y, acc[1][1]);
            acc[1][2] = fmaf(hb[j], w.z, acc[1][2]);
            acc[1][3] = fmaf(hb[j], w.w, acc[1][3]);
        }
    }
}

__global__ void deg_kernel(const int* __restrict__ rowi, float* __restrict__ deg, int E)
{
    int e = blockIdx.x * 256 + threadIdx.x;
    if (e < E) atomicAdd(&deg[rowi[e]], 1.0f);
}

// n8 = N*8 float4 elements
__global__ void node_mean_lrelu(const float* __restrict__ sum, const float* __restrict__ deg,
                                float* __restrict__ out, int n8)
{
    int i = blockIdx.x * 256 + threadIdx.x;
    if (i >= n8) return;
    float d = fmaxf(deg[i >> 3], 1.0f);
    float inv = 1.0f / d;
    float4 s = ((const float4*)sum)[i];
    float4 r;
    r.x = lrelu1(s.x * inv); r.y = lrelu1(s.y * inv);
    r.z = lrelu1(s.z * inv); r.w = lrelu1(s.w * inv);
    ((float4*)out)[i] = r;
}

// One edge-conv pass: h = [x[row], x[col], f0, (f1), (f2)]  (NCHUNK*32 features)
// edge_y2 = relu(h@w1+b1)@w2+b2 ; atomic-scatter y2 into nsum[row]; e_out = lrelu(y2)
// If FUSE: apply 3-layer edge MLP (lrelu, lrelu, none) to lrelu(y2) and store that.
template<int NCHUNK, bool FUSE>
__global__ __launch_bounds__(256)
void conv_kernel(const float* __restrict__ x,
                 const int* __restrict__ rowi, const int* __restrict__ coli,
                 const float* __restrict__ f0, const float* __restrict__ f1,
                 const float* __restrict__ f2,
                 const float* __restrict__ w1g, const float* __restrict__ b1g,
                 const float* __restrict__ w2g, const float* __restrict__ b2g,
                 const float* __restrict__ mw1g, const float* __restrict__ mb1g,
                 const float* __restrict__ mw2g, const float* __restrict__ mb2g,
                 const float* __restrict__ mw3g, const float* __restrict__ mb3g,
                 float* __restrict__ eout, float* __restrict__ nsum, int E)
{
    constexpr int IN = NCHUNK * 32;
    __shared__ float w1s[IN * 32];
    __shared__ float w2s[32 * 32];
    __shared__ float mws[FUSE ? 3 * 32 * 32 : 4];
    __shared__ float hs[64 * PAD];
    __shared__ float ys[64 * PAD];

    const int tid = threadIdx.x;

    // stage weights
    for (int i = tid; i < IN * 8; i += 256)
        ((float4*)w1s)[i] = ((const float4*)w1g)[i];
    ((float4*)w2s)[tid & 255] = ((const float4*)w2g)[tid & 255];
    if (FUSE) {
        ((float4*)mws)[tid] = ((const float4*)mw1g)[tid];
        ((float4*)(mws + 1024))[tid] = ((const float4*)mw2g)[tid];
        ((float4*)(mws + 2048))[tid] = ((const float4*)mw3g)[tid];
    }

    const int g  = tid & 7;        // channel group -> channels 4g..4g+3
    const int es = tid >> 3;       // edge slot 0..31 ; edges es and es+32
    const long long eb = (long long)blockIdx.x * 64;
    const long long eA = eb + es, eB = eA + 32;
    const bool vA = eA < E, vB = eB < E;
    const int rA = vA ? rowi[eA] : 0;
    const int rB = vB ? rowi[eB] : 0;

    float acc[2][4];
#pragma unroll
    for (int j = 0; j < 4; ++j) { acc[0][j] = b1g[4 * g + j]; acc[1][j] = acc[0][j]; }

    // ---- layer 1 over K chunks ----
    const int se = tid >> 2, sq = tid & 3;   // staging: edge slot, quarter-row
    long long sge = eb + se; if (sge >= E) sge = E - 1;
#pragma unroll
    for (int c = 0; c < NCHUNK; ++c) {
        __syncthreads();   // prior chunk readers done (also covers weight staging at c=0)
        const float* src;
        long long r;
        if (c == 0)      { src = x;  r = rowi[sge]; }
        else if (c == 1) { src = x;  r = coli[sge]; }
        else {
            src = (c == 2) ? f0 : (c == 3) ? f1 : f2;
            r = sge;
        }
        const float4* p = (const float4*)&src[r * 32 + sq * 8];
        float4 v0 = p[0], v1 = p[1];
        *(float4*)&hs[se * PAD + sq * 8]     = v0;
        *(float4*)&hs[se * PAD + sq * 8 + 4] = v1;
        __syncthreads();
        gemm32_acc(&w1s[c * 1024], hs, es, g, acc);
    }

    // relu -> ys
    *(float4*)&ys[es * PAD + 4 * g]        = relu4(acc[0]);
    *(float4*)&ys[(es + 32) * PAD + 4 * g] = relu4(acc[1]);
    __syncthreads();

    // ---- layer 2 ----
    float acc2[2][4];
#pragma unroll
    for (int j = 0; j < 4; ++j) { acc2[0][j] = b2g[4 * g + j]; acc2[1][j] = acc2[0][j]; }
    gemm32_acc(w2s, ys, es, g, acc2);

    // scatter-add (pre-activation) into node sums
#pragma unroll
    for (int j = 0; j < 4; ++j) {
        if (vA) atomicAdd(&nsum[(long long)rA * 32 + 4 * g + j], acc2[0][j]);
        if (vB) atomicAdd(&nsum[(long long)rB * 32 + 4 * g + j], acc2[1][j]);
    }

    float4 oA = lrelu4(acc2[0]);
    float4 oB = lrelu4(acc2[1]);

    if (!FUSE) {
        if (vA) *(float4*)&eout[eA * 32 + 4 * g] = oA;
        if (vB) *(float4*)&eout[eB * 32 + 4 * g] = oB;
    } else {
        // e3 = lrelu(y2) -> hs (safe: all hs readers passed the ys barrier)
        *(float4*)&hs[es * PAD + 4 * g]        = oA;
        *(float4*)&hs[(es + 32) * PAD + 4 * g] = oB;
        __syncthreads();

        float m[2][4];
        // MLP layer 1: hs -> ys (lrelu)
#pragma unroll
        for (int j = 0; j < 4; ++j) { m[0][j] = mb1g[4 * g + j]; m[1][j] = m[0][j]; }
        gemm32_acc(mws, hs, es, g, m);
        *(float4*)&ys[es * PAD + 4 * g]        = lrelu4(m[0]);
        *(float4*)&ys[(es + 32) * PAD + 4 * g] = lrelu4(m[1]);
        __syncthreads();
        // MLP layer 2: ys -> hs (lrelu)
#pragma unroll
        for (int j = 0; j < 4; ++j) { m[0][j] = mb2g[4 * g + j]; m[1][j] = m[0][j]; }
        gemm32_acc(mws + 1024, ys, es, g, m);
        *(float4*)&hs[es * PAD + 4 * g]        = lrelu4(m[0]);
        *(float4*)&hs[(es + 32) * PAD + 4 * g] = lrelu4(m[1]);
        __syncthreads();
        // MLP layer 3: hs -> global (no act)
#pragma unroll
        for (int j = 0; j < 4; ++j) { m[0][j] = mb3g[4 * g + j]; m[1][j] = m[0][j]; }
        gemm32_acc(mws + 2048, hs, es, g, m);
        if (vA) *(float4*)&eout[eA * 32 + 4 * g] = make_float4(m[0][0], m[0][1], m[0][2], m[0][3]);
        if (vB) *(float4*)&eout[eB * 32 + 4 * g] = make_float4(m[1][0], m[1][1], m[1][2], m[1][3]);
    }
}

// n3 = lrelu(sum/deg); out = lrelu(lrelu(n3@w1+b1)@w2+b2)@w3+b3
__global__ __launch_bounds__(256)
void node_final(const float* __restrict__ sum, const float* __restrict__ deg,
                const float* __restrict__ w1g, const float* __restrict__ b1g,
                const float* __restrict__ w2g, const float* __restrict__ b2g,
                const float* __restrict__ w3g, const float* __restrict__ b3g,
                float* __restrict__ out, int N)
{
    __shared__ float ws1[1024], ws2[1024], ws3[1024];
    __shared__ float hs[64 * PAD];
    __shared__ float ys[64 * PAD];

    const int tid = threadIdx.x;
    ((float4*)ws1)[tid] = ((const float4*)w1g)[tid];
    ((float4*)ws2)[tid] = ((const float4*)w2g)[tid];
    ((float4*)ws3)[tid] = ((const float4*)w3g)[tid];

    const int g  = tid & 7;
    const int vs = tid >> 3;
    const long long vb = (long long)blockIdx.x * 64;
    const long long nA = vb + vs, nB = nA + 32;

    // stage n3 rows
    const int se = tid >> 2, sq = tid & 3;
    long long v = vb + se;
    float4 a0 = make_float4(0, 0, 0, 0), a1 = a0;
    if (v < N) {
        float inv = 1.0f / fmaxf(deg[v], 1.0f);
        float4 s0 = *(const float4*)&sum[v * 32 + sq * 8];
        float4 s1 = *(const float4*)&sum[v * 32 + sq * 8 + 4];
        a0.x = lrelu1(s0.x * inv); a0.y = lrelu1(s0.y * inv);
        a0.z = lrelu1(s0.z * inv); a0.w = lrelu1(s0.w * inv);
        a1.x = lrelu1(s1.x * inv); a1.y = lrelu1(s1.y * inv);
        a1.z = lrelu1(s1.z * inv); a1.w = lrelu1(s1.w * inv);
    }
    *(float4*)&hs[se * PAD + sq * 8]     = a0;
    *(float4*)&hs[se * PAD + sq * 8 + 4] = a1;
    __syncthreads();

    float m[2][4];
#pragma unroll
    for (int j = 0; j < 4; ++j) { m[0][j] = b1g[4 * g + j]; m[1][j] = m[0][j]; }
    gemm32_acc(ws1, hs, vs, g, m);
    *(float4*)&ys[vs * PAD + 4 * g]        = lrelu4(m[0]);
    *(float4*)&ys[(vs + 32) * PAD + 4 * g] = lrelu4(m[1]);
    __syncthreads();

#pragma unroll
    for (int j = 0; j < 4; ++j) { m[0][j] = b2g[4 * g + j]; m[1][j] = m[0][j]; }
    gemm32_acc(ws2, ys, vs, g, m);
    *(float4*)&hs[vs * PAD + 4 * g]        = lrelu4(m[0]);
    *(float4*)&hs[(vs + 32) * PAD + 4 * g] = lrelu4(m[1]);
    __syncthreads();

#pragma unroll
    for (int j = 0; j < 4; ++j) { m[0][j] = b3g[4 * g + j]; m[1][j] = m[0][j]; }
    gemm32_acc(ws3, hs, vs, g, m);
    if (nA < N) *(float4*)&out[nA * 32 + 4 * g] = make_float4(m[0][0], m[0][1], m[0][2], m[0][3]);
    if (nB < N) *(float4*)&out[nB * 32 + 4 * g] = make_float4(m[1][0], m[1][1], m[1][2], m[1][3]);
}

extern "C" void kernel_launch(void* const* d_in, const int* in_sizes, int n_in,
                              void* d_out, int out_size, void* d_ws, size_t ws_size,
                              hipStream_t stream)
{
    const float* node_attr = (const float*)d_in[0];
    const float* edge_attr = (const float*)d_in[1];
    const int*   eidx      = (const int*)d_in[2];
    const float* c1w1 = (const float*)d_in[3];  const float* c1b1 = (const float*)d_in[4];
    const float* c1w2 = (const float*)d_in[5];  const float* c1b2 = (const float*)d_in[6];
    const float* c2w1 = (const float*)d_in[7];  const float* c2b1 = (const float*)d_in[8];
    const float* c2w2 = (const float*)d_in[9];  const float* c2b2 = (const float*)d_in[10];
    const float* c3w1 = (const float*)d_in[11]; const float* c3b1 = (const float*)d_in[12];
    const float* c3w2 = (const float*)d_in[13]; const float* c3b2 = (const float*)d_in[14];
    const float* nw1  = (const float*)d_in[15]; const float* nb1  = (const float*)d_in[16];
    const float* nw2  = (const float*)d_in[17]; const float* nb2  = (const float*)d_in[18];
    const float* nw3  = (const float*)d_in[19]; const float* nb3  = (const float*)d_in[20];
    const float* ew1  = (const float*)d_in[21]; const float* eb1  = (const float*)d_in[22];
    const float* ew2  = (const float*)d_in[23]; const float* eb2  = (const float*)d_in[24];
    const float* ew3  = (const float*)d_in[25]; const float* eb3  = (const float*)d_in[26];

    const int N = in_sizes[0] / 32;
    const int E = in_sizes[1] / 32;
    const int* rowi = eidx;
    const int* coli = eidx + E;

    float* out      = (float*)d_out;
    float* node_out = out;                       // N*32
    float* edge_out = out + (size_t)N * 32;      // E*32

    // workspace layout (floats)
    float* ws   = (float*)d_ws;
    float* deg  = ws;                              // N
    float* sum1 = ws + N;                          // 32N
    float* sum2 = sum1 + (size_t)32 * N;           // 32N
    float* sum3 = sum2 + (size_t)32 * N;           // 32N
    float* n1   = sum3 + (size_t)32 * N;           // 32N
    float* n2   = n1   + (size_t)32 * N;           // 32N
    float* e1   = n2   + (size_t)32 * N;           // 32E
    float* e2   = e1   + (size_t)32 * E;           // 32E

    // zero deg + sum1..3 (contiguous 97N floats)
    hipMemsetAsync(deg, 0, (size_t)97 * N * sizeof(float), stream);

    deg_kernel<<<(E + 255) / 256, 256, 0, stream>>>(rowi, deg, E);

    const int convGrid = (E + 63) / 64;
    conv_kernel<3, false><<<convGrid, 256, 0, stream>>>(
        node_attr, rowi, coli, edge_attr, nullptr, nullptr,
        c1w1, c1b1, c1w2, c1b2,
        nullptr, nullptr, nullptr, nullptr, nullptr, nullptr,
        e1, sum1, E);

    node_mean_lrelu<<<(N * 8 + 255) / 256, 256, 0, stream>>>(sum1, deg, n1, N * 8);

    conv_kernel<4, false><<<convGrid, 256, 0, stream>>>(
        n1, rowi, coli, e1, edge_attr, nullptr,
        c2w1, c2b1, c2w2, c2b2,
        nullptr, nullptr, nullptr, nullptr, nullptr, nullptr,
        e2, sum2, E);

    node_mean_lrelu<<<(N * 8 + 255) / 256, 256, 0, stream>>>(sum2, deg, n2, N * 8);

    conv_kernel<5, true><<<convGrid, 256, 0, stream>>>(
        n2, rowi, coli, e2, e1, edge_attr,
        c3w1, c3b1, c3w2, c3b2,
        ew1, eb1, ew2, eb2, ew3, eb3,
        edge_out, sum3, E);

    node_final<<<(N + 63) / 64, 256, 0, stream>>>(
        sum3, deg, nw1, nb1, nw2, nb2, nw3, nb3, node_out, N);
}

// Round 2
// 2251.312 us; speedup vs baseline: 1.2147x; 1.2147x over previous
//
#include <hip/hip_runtime.h>

#define DEVINL __device__ __forceinline__

constexpr int PADF = 36;   // LDS row stride in floats (144B: 16B-aligned, breaks 32-bank alias)

DEVINL float lrelu1(float v)    { return v > 0.f ? v : 0.2f * v; }
DEVINL float invlrelu1(float v) { return v > 0.f ? v : 5.0f * v; }

// acc[32] += hrow(32 floats, LDS) @ wg[32][32] (global, wave-uniform addresses)
DEVINL void gemm_block(const float* __restrict__ wg, const float* hrow, float acc[32])
{
#pragma unroll
    for (int cb = 0; cb < 4; ++cb) {
#pragma unroll 1
        for (int kq = 0; kq < 8; ++kq) {
            float4 h = *(const float4*)(hrow + kq * 4);
#pragma unroll
            for (int i = 0; i < 4; ++i) {
                float hv = ((const float*)&h)[i];
                float w8[8];
                *(float4*)&w8[0] = *(const float4*)(wg + (kq * 4 + i) * 32 + cb * 8);
                *(float4*)&w8[4] = *(const float4*)(wg + (kq * 4 + i) * 32 + cb * 8 + 4);
#pragma unroll
                for (int jj = 0; jj < 8; ++jj)
                    acc[cb * 8 + jj] = fmaf(hv, w8[jj], acc[cb * 8 + jj]);
            }
        }
    }
}

// ---------------- CSR build ----------------
__global__ __launch_bounds__(256)
void hist_kernel(const int* __restrict__ rowi, int* __restrict__ deg, int E)
{
    int e = blockIdx.x * 256 + threadIdx.x;
    if (e < E) atomicAdd(&deg[rowi[e]], 1);
}

__global__ __launch_bounds__(256)
void scan_kernel(const int* __restrict__ deg, int* __restrict__ off,
                 int* __restrict__ cursor, int N, int E)
{
    __shared__ int part[256];
    __shared__ int psum[256];
    const int t = threadIdx.x;
    const int per = (N + 255) / 256;
    const int b0 = t * per;
    int s = 0;
    for (int i = 0; i < per; ++i) { int idx = b0 + i; if (idx < N) s += deg[idx]; }
    part[t] = s;
    __syncthreads();
    if (t == 0) { int run = 0; for (int i = 0; i < 256; ++i) { psum[i] = run; run += part[i]; } }
    __syncthreads();
    int run = psum[t];
    for (int i = 0; i < per; ++i) {
        int idx = b0 + i;
        if (idx < N) { off[idx] = run; cursor[idx] = run; run += deg[idx]; }
    }
    if (t == 0) off[N] = E;
}

__global__ __launch_bounds__(256)
void place_kernel(const int* __restrict__ rowi, int* __restrict__ cursor,
                  int* __restrict__ perm, int E)
{
    int e = blockIdx.x * 256 + threadIdx.x;
    if (e < E) {
        int r = rowi[e];
        int p = atomicAdd(&cursor[r], 1);
        perm[p] = e;
    }
}

// ---------------- edge conv (layer1 over NCHUNK K-chunks + layer2) ----------------
// h = [x[row], x[col], f0, (f1), (f2)]; eout[e] = lrelu(relu(h@w1+b1)@w2+b2)
template<int NCHUNK>
__global__ __launch_bounds__(256)
void conv_kernel(const float* __restrict__ x,
                 const int* __restrict__ rowi, const int* __restrict__ coli,
                 const float* __restrict__ f0, const float* __restrict__ f1,
                 const float* __restrict__ f2,
                 const float* __restrict__ w1g, const float* __restrict__ b1g,
                 const float* __restrict__ w2g, const float* __restrict__ b2g,
                 float* __restrict__ eout, int E)
{
    __shared__ float hs[256 * PADF];
    const int tid = threadIdx.x;
    const int base = blockIdx.x * 256;
    const int se = tid >> 3;      // staging row (within a 32-row pass)
    const int sq = tid & 7;       // float4 quad within row
    const float* hrow = hs + tid * PADF;

    float acc[32];
#pragma unroll
    for (int j = 0; j < 32; ++j) acc[j] = b1g[j];

#pragma unroll
    for (int c = 0; c < NCHUNK; ++c) {
        __syncthreads();
#pragma unroll 1
        for (int p = 0; p < 8; ++p) {
            int lr = p * 32 + se;          // local row 0..255
            int e = base + lr; if (e >= E) e = E - 1;
            const float* src;
            int r;
            if (c == 0)      { src = x;  r = rowi[e]; }
            else if (c == 1) { src = x;  r = coli[e]; }
            else { src = (c == 2) ? f0 : (c == 3) ? f1 : f2; r = e; }
            float4 v = *(const float4*)(src + (long long)r * 32 + sq * 4);
            *(float4*)&hs[lr * PADF + sq * 4] = v;
        }
        __syncthreads();
        gemm_block(w1g + c * 1024, hrow, acc);
    }

    // relu -> LDS -> layer 2
    __syncthreads();
#pragma unroll
    for (int j = 0; j < 32; j += 4) {
        float4 v;
        v.x = fmaxf(acc[j],     0.f); v.y = fmaxf(acc[j + 1], 0.f);
        v.z = fmaxf(acc[j + 2], 0.f); v.w = fmaxf(acc[j + 3], 0.f);
        *(float4*)&hs[tid * PADF + j] = v;
    }
    __syncthreads();

    float acc2[32];
#pragma unroll
    for (int j = 0; j < 32; ++j) acc2[j] = b2g[j];
    gemm_block(w2g, hrow, acc2);

    int e = base + tid;
    if (e < E) {
#pragma unroll
        for (int j = 0; j < 32; j += 4) {
            float4 v;
            v.x = lrelu1(acc2[j]);     v.y = lrelu1(acc2[j + 1]);
            v.z = lrelu1(acc2[j + 2]); v.w = lrelu1(acc2[j + 3]);
            *(float4*)(eout + (long long)e * 32 + j) = v;
        }
    }
}

// ---------------- CSR scatter-mean (gather form) ----------------
// nout[n] = lrelu( mean_e(invlrelu(esrc[e])) )   over node n's edge list
__global__ __launch_bounds__(256)
void mean_kernel(const float* __restrict__ esrc, const int* __restrict__ off,
                 const int* __restrict__ perm, float* __restrict__ nout, int N)
{
    const int t = threadIdx.x;
    const int n = blockIdx.x * 32 + (t >> 3);
    if (n >= N) return;
    const int cg = t & 7;
    const int o0 = off[n], o1 = off[n + 1];
    float4 acc = make_float4(0.f, 0.f, 0.f, 0.f);
    for (int i = o0; i < o1; ++i) {
        int e = perm[i];
        float4 v = *(const float4*)(esrc + (long long)e * 32 + cg * 4);
        acc.x += invlrelu1(v.x); acc.y += invlrelu1(v.y);
        acc.z += invlrelu1(v.z); acc.w += invlrelu1(v.w);
    }
    float inv = 1.0f / (float)max(o1 - o0, 1);
    float4 r;
    r.x = lrelu1(acc.x * inv); r.y = lrelu1(acc.y * inv);
    r.z = lrelu1(acc.z * inv); r.w = lrelu1(acc.w * inv);
    *(float4*)(nout + (long long)n * 32 + cg * 4) = r;
}

// ---------------- 3-layer 32->32 MLP (lrelu, lrelu, none) ----------------
// out[m] = lrelu(lrelu(in[m]@w1+b1)@w2+b2)@w3+b3 ; safe in-place (row-owned)
__global__ __launch_bounds__(256)
void mlp3_kernel(const float* __restrict__ in,
                 const float* __restrict__ w1g, const float* __restrict__ b1g,
                 const float* __restrict__ w2g, const float* __restrict__ b2g,
                 const float* __restrict__ w3g, const float* __restrict__ b3g,
                 float* __restrict__ out, int M)
{
    __shared__ float hs[256 * PADF];
    const int tid = threadIdx.x;
    const int base = blockIdx.x * 256;
    const int se = tid >> 3;
    const int sq = tid & 7;
    const float* hrow = hs + tid * PADF;

#pragma unroll 1
    for (int p = 0; p < 8; ++p) {
        int lr = p * 32 + se;
        int m = base + lr; if (m >= M) m = M - 1;
        float4 v = *(const float4*)(in + (long long)m * 32 + sq * 4);
        *(float4*)&hs[lr * PADF + sq * 4] = v;
    }
    __syncthreads();

    float acc[32];
#pragma unroll
    for (int j = 0; j < 32; ++j) acc[j] = b1g[j];
    gemm_block(w1g, hrow, acc);
    __syncthreads();
#pragma unroll
    for (int j = 0; j < 32; j += 4) {
        float4 v;
        v.x = lrelu1(acc[j]);     v.y = lrelu1(acc[j + 1]);
        v.z = lrelu1(acc[j + 2]); v.w = lrelu1(acc[j + 3]);
        *(float4*)&hs[tid * PADF + j] = v;
    }
    __syncthreads();

#pragma unroll
    for (int j = 0; j < 32; ++j) acc[j] = b2g[j];
    gemm_block(w2g, hrow, acc);
    __syncthreads();
#pragma unroll
    for (int j = 0; j < 32; j += 4) {
        float4 v;
        v.x = lrelu1(acc[j]);     v.y = lrelu1(acc[j + 1]);
        v.z = lrelu1(acc[j + 2]); v.w = lrelu1(acc[j + 3]);
        *(float4*)&hs[tid * PADF + j] = v;
    }
    __syncthreads();

#pragma unroll
    for (int j = 0; j < 32; ++j) acc[j] = b3g[j];
    gemm_block(w3g, hrow, acc);

    int m = base + tid;
    if (m < M) {
#pragma unroll
        for (int j = 0; j < 32; j += 4) {
            float4 v = make_float4(acc[j], acc[j + 1], acc[j + 2], acc[j + 3]);
            *(float4*)(out + (long long)m * 32 + j) = v;
        }
    }
}

extern "C" void kernel_launch(void* const* d_in, const int* in_sizes, int n_in,
                              void* d_out, int out_size, void* d_ws, size_t ws_size,
                              hipStream_t stream)
{
    const float* node_attr = (const float*)d_in[0];
    const float* edge_attr = (const float*)d_in[1];
    const int*   eidx      = (const int*)d_in[2];
    const float* c1w1 = (const float*)d_in[3];  const float* c1b1 = (const float*)d_in[4];
    const float* c1w2 = (const float*)d_in[5];  const float* c1b2 = (const float*)d_in[6];
    const float* c2w1 = (const float*)d_in[7];  const float* c2b1 = (const float*)d_in[8];
    const float* c2w2 = (const float*)d_in[9];  const float* c2b2 = (const float*)d_in[10];
    const float* c3w1 = (const float*)d_in[11]; const float* c3b1 = (const float*)d_in[12];
    const float* c3w2 = (const float*)d_in[13]; const float* c3b2 = (const float*)d_in[14];
    const float* nw1  = (const float*)d_in[15]; const float* nb1  = (const float*)d_in[16];
    const float* nw2  = (const float*)d_in[17]; const float* nb2  = (const float*)d_in[18];
    const float* nw3  = (const float*)d_in[19]; const float* nb3  = (const float*)d_in[20];
    const float* ew1  = (const float*)d_in[21]; const float* eb1  = (const float*)d_in[22];
    const float* ew2  = (const float*)d_in[23]; const float* eb2  = (const float*)d_in[24];
    const float* ew3  = (const float*)d_in[25]; const float* eb3  = (const float*)d_in[26];

    const int N = in_sizes[0] / 32;
    const int E = in_sizes[1] / 32;
    const int* rowi = eidx;
    const int* coli = eidx + E;

    float* out      = (float*)d_out;
    float* node_out = out;                       // N*32
    float* edge_out = out + (size_t)N * 32;      // E*32 (also used as e3 scratch)

    // workspace: ints first, then 256B-aligned floats
    int* deg    = (int*)d_ws;                    // N
    int* off    = deg + N;                       // N+1
    int* cursor = off + (N + 1);                 // N
    int* perm   = cursor + N;                    // E
    uintptr_t a = ((uintptr_t)(perm + E) + 255) & ~(uintptr_t)255;
    float* n1 = (float*)a;                       // 32N
    float* n2 = n1 + (size_t)32 * N;             // 32N
    float* n3 = n1;                              // alias: n1 dead after conv2
    float* e1 = n2 + (size_t)32 * N;             // 32E
    float* e2 = e1 + (size_t)32 * E;             // 32E

    const int gridE = (E + 255) / 256;
    const int gridN32 = (N + 31) / 32;
    const int gridN = (N + 255) / 256;

    // ---- CSR build (once, reused by all 3 convs) ----
    hipMemsetAsync(deg, 0, (size_t)N * sizeof(int), stream);
    hist_kernel<<<gridE, 256, 0, stream>>>(rowi, deg, E);
    scan_kernel<<<1, 256, 0, stream>>>(deg, off, cursor, N, E);
    place_kernel<<<gridE, 256, 0, stream>>>(rowi, cursor, perm, E);

    // ---- conv1 ----
    conv_kernel<3><<<gridE, 256, 0, stream>>>(
        node_attr, rowi, coli, edge_attr, nullptr, nullptr,
        c1w1, c1b1, c1w2, c1b2, e1, E);
    mean_kernel<<<gridN32, 256, 0, stream>>>(e1, off, perm, n1, N);

    // ---- conv2 ----
    conv_kernel<4><<<gridE, 256, 0, stream>>>(
        n1, rowi, coli, e1, edge_attr, nullptr,
        c2w1, c2b1, c2w2, c2b2, e2, E);
    mean_kernel<<<gridN32, 256, 0, stream>>>(e2, off, perm, n2, N);

    // ---- conv3 (e3 parked in edge_out region) ----
    conv_kernel<5><<<gridE, 256, 0, stream>>>(
        n2, rowi, coli, e2, e1, edge_attr,
        c3w1, c3b1, c3w2, c3b2, edge_out, E);
    mean_kernel<<<gridN32, 256, 0, stream>>>(edge_out, off, perm, n3, N);

    // ---- output MLPs (edge MLP reads e3 from edge_out, writes in place AFTER mean3) ----
    mlp3_kernel<<<gridE, 256, 0, stream>>>(edge_out, ew1, eb1, ew2, eb2, ew3, eb3,
                                           edge_out, E);
    mlp3_kernel<<<gridN, 256, 0, stream>>>(n3, nw1, nb1, nw2, nb2, nw3, nb3,
                                           node_out, N);
}